// Round 12
// baseline (509.732 us; speedup 1.0000x reference)
//
#include <hip/hip_runtime.h>
#include <math.h>

// GATv2 x3 + log_softmax for MI355X (gfx950).
// Round 12: kill the GEMM's hidden VALU cost.
//   R11 analysis: loadA does ~290 VALU ops/lane (act + bf16 split of 32 f32)
//   vs 240 cyc of MFMA -> GEMM was an activation kernel with MFMAs attached.
//   Now: A lives in memory as split bf16 (ah, al).
//     - k_prepX splits x once (layer 1)
//     - k_edge4 epilogue applies next layer's act (ELU/ReLU) and writes split
//       bf16 directly (f32 bufA round-trip deleted)
//     - GEMMs load A as short8 (zero per-element VALU)
// Edge gather/score math unchanged from R9-R11.

#define TPB 256

typedef __attribute__((ext_vector_type(8))) short short8v;   // 8 bf16
typedef __attribute__((ext_vector_type(4))) float f32x4;

__device__ __forceinline__ short bf16rne(float v, float* recon) {
  unsigned u = __float_as_uint(v);
  unsigned r = (u + 0x7FFFu + ((u >> 16) & 1u)) >> 16;
  if (recon) *recon = __uint_as_float(r << 16);
  return (short)r;
}
__device__ __forceinline__ float bf2f(unsigned short u) {
  return __uint_as_float((unsigned)u << 16);
}

// ---------------- x -> (ah, al) split bf16, no act ----------------
__global__ void k_prepX(const float* __restrict__ x, unsigned short* __restrict__ ah,
                        unsigned short* __restrict__ al, int total8) {
  int t = blockIdx.x * blockDim.x + threadIdx.x;
  if (t >= total8) return;
  const float4* px = reinterpret_cast<const float4*>(x) + (size_t)t * 2;
  float4 a = px[0], b = px[1];
  float av[8] = {a.x, a.y, a.z, a.w, b.x, b.y, b.z, b.w};
  short8v h, l;
#pragma unroll
  for (int j = 0; j < 8; ++j) {
    float vh;
    h[j] = bf16rne(av[j], &vh);
    l[j] = bf16rne(av[j] - vh, nullptr);
  }
  *reinterpret_cast<short8v*>(ah + (size_t)t * 8) = h;
  *reinterpret_cast<short8v*>(al + (size_t)t * 8) = l;
}

// ---------------- merged W preprocess ----------------
__global__ void k_prepW6(const float* __restrict__ s0, const float* __restrict__ s1,
                         const float* __restrict__ s2, const float* __restrict__ s3,
                         const float* __restrict__ s4, const float* __restrict__ s5,
                         short* __restrict__ wt) {
  int y = blockIdx.y;
  const float* W; short* hi; int M, Mp;
  if (y < 4) {
    W = (y == 0) ? s0 : (y == 1) ? s1 : (y == 2) ? s2 : s3;
    hi = wt + y * 32768; M = 128; Mp = 128;
  } else {
    W = (y == 4) ? s4 : s5;
    hi = wt + 131072 + (y - 4) * 12288; M = 40; Mp = 48;
  }
  short* lo = hi + 128 * Mp;
  int t = blockIdx.x * blockDim.x + threadIdx.x;
  if (t >= 128 * Mp) return;
  int m = t % Mp, k = t / Mp;
  float v = (m < M) ? W[k * M + m] : 0.f;
  float vh;
  short h = bf16rne(v, &vh);
  short l = bf16rne(v - vh, nullptr);
  hi[(size_t)m * 128 + k] = h;
  lo[(size_t)m * 128 + k] = l;
}

// ---------------- MFMA GEMM M=128: 16 rows/block, wave w -> cols {2w,2w+1} ----
// A read as pre-split bf16; zero per-element VALU in the kernel.
__global__ __launch_bounds__(256) void k_gemm_mfma(
    const unsigned short* __restrict__ ah, const unsigned short* __restrict__ al,
    const short* __restrict__ blh, const short* __restrict__ bll,
    const short* __restrict__ brh, const short* __restrict__ brl,
    unsigned short* __restrict__ glh, float* __restrict__ gr, int n) {
  const int K = 128;
  int lane = threadIdx.x & 63;
  int w = threadIdx.x >> 6;          // 0..3
  int rbase = blockIdx.x * 16;
  int arow = rbase + (lane & 15);
  if (arow >= n) arow = n - 1;
  int koff = (lane >> 4) * 8;

  short8v AH[4], AL[4];
#pragma unroll
  for (int k = 0; k < 4; ++k) {
    AH[k] = *reinterpret_cast<const short8v*>(ah + (size_t)arow * 128 + k * 32 + koff);
    AL[k] = *reinterpret_cast<const short8v*>(al + (size_t)arow * 128 + k * 32 + koff);
  }

  f32x4 acc[2][2];
#pragma unroll
  for (int m = 0; m < 2; ++m)
#pragma unroll
    for (int c = 0; c < 2; ++c) acc[m][c] = (f32x4)(0.f);

  int bbase = (lane & 15) * K + koff;
  const int cb = w * 2;

#define BOFF(IT) (((cb + ((IT) & 1)) * 16 * K) + bbase + (((IT) >> 1) * 32))
  short8v cbh = *reinterpret_cast<const short8v*>(blh + BOFF(0));
  short8v cbl = *reinterpret_cast<const short8v*>(bll + BOFF(0));
  short8v cch = *reinterpret_cast<const short8v*>(brh + BOFF(0));
  short8v ccl = *reinterpret_cast<const short8v*>(brl + BOFF(0));
#pragma unroll
  for (int it = 0; it < 8; ++it) {
    const int k0i = it >> 1, ci = it & 1;
    const int nit = (it + 1) & 7;
    short8v nbh = *reinterpret_cast<const short8v*>(blh + BOFF(nit));
    short8v nbl = *reinterpret_cast<const short8v*>(bll + BOFF(nit));
    short8v nch = *reinterpret_cast<const short8v*>(brh + BOFF(nit));
    short8v ncl = *reinterpret_cast<const short8v*>(brl + BOFF(nit));
    acc[0][ci] = __builtin_amdgcn_mfma_f32_16x16x32_bf16(AH[k0i], cbh, acc[0][ci], 0, 0, 0);
    acc[0][ci] = __builtin_amdgcn_mfma_f32_16x16x32_bf16(AH[k0i], cbl, acc[0][ci], 0, 0, 0);
    acc[0][ci] = __builtin_amdgcn_mfma_f32_16x16x32_bf16(AL[k0i], cbh, acc[0][ci], 0, 0, 0);
    acc[1][ci] = __builtin_amdgcn_mfma_f32_16x16x32_bf16(AH[k0i], cch, acc[1][ci], 0, 0, 0);
    acc[1][ci] = __builtin_amdgcn_mfma_f32_16x16x32_bf16(AH[k0i], ccl, acc[1][ci], 0, 0, 0);
    acc[1][ci] = __builtin_amdgcn_mfma_f32_16x16x32_bf16(AL[k0i], cch, acc[1][ci], 0, 0, 0);
    cbh = nbh; cbl = nbl; cch = nch; ccl = ncl;
  }
#undef BOFF

  int crow = rbase + (lane >> 4) * 4;
  int ccol = lane & 15;
#pragma unroll
  for (int ci = 0; ci < 2; ++ci) {
    int c = cb + ci;
#pragma unroll
    for (int j = 0; j < 4; ++j) {
      int r = crow + j;
      if (r < n) {
        glh[(size_t)r * 128 + c * 16 + ccol] = (unsigned short)bf16rne(acc[0][ci][j], nullptr);
        gr[(size_t)r * 128 + c * 16 + ccol] = acc[1][ci][j];
      }
    }
  }
}

// ---------------- MFMA GEMM M=40 (pad 48): 16 rows/block, wave w -> col w ------
__global__ __launch_bounds__(192) void k_gemm_mfma3(
    const unsigned short* __restrict__ ah, const unsigned short* __restrict__ al,
    const short* __restrict__ blh, const short* __restrict__ bll,
    const short* __restrict__ brh, const short* __restrict__ brl,
    unsigned short* __restrict__ glh, float* __restrict__ gr, int n) {
  const int K = 128;
  int lane = threadIdx.x & 63;
  int w = threadIdx.x >> 6;          // 0..2
  int rbase = blockIdx.x * 16;
  int arow = rbase + (lane & 15);
  if (arow >= n) arow = n - 1;
  int koff = (lane >> 4) * 8;

  short8v AH[4], AL[4];
#pragma unroll
  for (int k = 0; k < 4; ++k) {
    AH[k] = *reinterpret_cast<const short8v*>(ah + (size_t)arow * 128 + k * 32 + koff);
    AL[k] = *reinterpret_cast<const short8v*>(al + (size_t)arow * 128 + k * 32 + koff);
  }

  int bbase = w * 16 * K + (lane & 15) * K + koff;

  short8v Bh[4], Bl[4], Ch[4], Cl[4];
#pragma unroll
  for (int k = 0; k < 4; ++k) {
    Bh[k] = *reinterpret_cast<const short8v*>(blh + bbase + k * 32);
    Bl[k] = *reinterpret_cast<const short8v*>(bll + bbase + k * 32);
    Ch[k] = *reinterpret_cast<const short8v*>(brh + bbase + k * 32);
    Cl[k] = *reinterpret_cast<const short8v*>(brl + bbase + k * 32);
  }

  f32x4 accL = (f32x4)(0.f), accR = (f32x4)(0.f);
#pragma unroll
  for (int k = 0; k < 4; ++k) {
    accL = __builtin_amdgcn_mfma_f32_16x16x32_bf16(AH[k], Bh[k], accL, 0, 0, 0);
    accL = __builtin_amdgcn_mfma_f32_16x16x32_bf16(AH[k], Bl[k], accL, 0, 0, 0);
    accL = __builtin_amdgcn_mfma_f32_16x16x32_bf16(AL[k], Bh[k], accL, 0, 0, 0);
    accR = __builtin_amdgcn_mfma_f32_16x16x32_bf16(AH[k], Ch[k], accR, 0, 0, 0);
    accR = __builtin_amdgcn_mfma_f32_16x16x32_bf16(AH[k], Cl[k], accR, 0, 0, 0);
    accR = __builtin_amdgcn_mfma_f32_16x16x32_bf16(AL[k], Ch[k], accR, 0, 0, 0);
  }

  int crow = rbase + (lane >> 4) * 4;
  int ccol = lane & 15;
  int col = w * 16 + ccol;
#pragma unroll
  for (int j = 0; j < 4; ++j) {
    int r = crow + j;
    if (r < n && col < 40) {
      glh[(size_t)r * 40 + col] = (unsigned short)bf16rne(accL[j], nullptr);
      gr[(size_t)r * 40 + col] = accR[j];
    }
  }
}

// ---------------- CSR build ----------------
__global__ void k_hist(const int* __restrict__ dst, int* __restrict__ cnt, int E) {
  int e = blockIdx.x * blockDim.x + threadIdx.x;
  if (e < E) atomicAdd(&cnt[dst[e]], 1);
}

__global__ void k_scan1(const int* __restrict__ cnt, int* __restrict__ rowptr,
                        int* __restrict__ bsum, int n) {
  __shared__ int wsum[16];
  int i = blockIdx.x * 1024 + threadIdx.x;
  int lane = threadIdx.x & 63, wid = threadIdx.x >> 6;
  int v = (i < n) ? cnt[i] : 0;
  int x = v;
#pragma unroll
  for (int off = 1; off < 64; off <<= 1) {
    int t = __shfl_up(x, off);
    if (lane >= off) x += t;
  }
  if (lane == 63) wsum[wid] = x;
  __syncthreads();
  if (wid == 0) {
    int wv = (lane < 16) ? wsum[lane] : 0;
#pragma unroll
    for (int off = 1; off < 16; off <<= 1) {
      int t = __shfl_up(wv, off);
      if (lane >= off) wv += t;
    }
    if (lane < 16) wsum[lane] = wv;
  }
  __syncthreads();
  int woff = wid ? wsum[wid - 1] : 0;
  if (i < n) rowptr[i] = woff + x - v;
  if (threadIdx.x == 1023) bsum[blockIdx.x] = wsum[15];
}

__global__ void k_scan2(const int* __restrict__ bsum, int* __restrict__ boff, int nb,
                        int* __restrict__ rowptr, int n) {
  int lane = threadIdx.x;
  int v = (lane < nb) ? bsum[lane] : 0;
  int x = v;
#pragma unroll
  for (int off = 1; off < 64; off <<= 1) {
    int t = __shfl_up(x, off);
    if (lane >= off) x += t;
  }
  if (lane < nb) boff[lane] = x - v;
  if (lane == 63) rowptr[n] = x;
}

__global__ void k_scan3(int* __restrict__ rowptr, const int* __restrict__ boff,
                        int* __restrict__ cur, int n) {
  int i = blockIdx.x * blockDim.x + threadIdx.x;
  if (i < n) {
    int r = rowptr[i] + boff[i >> 10];
    rowptr[i] = r;
    cur[i] = r;
  }
}

__global__ void k_fill(const int* __restrict__ src, const int* __restrict__ dst,
                       int* __restrict__ cur, int* __restrict__ csr_src, int E) {
  int e = blockIdx.x * blockDim.x + threadIdx.x;
  if (e >= E) return;
  int pos = atomicAdd(&cur[dst[e]], 1);
  csr_src[pos] = src[e];
}

// ---- fused per-dst edge kernel, H=4 F=32, 8 chains, no-max ----
// ACTOUT: 1 = ELU, 2 = ReLU applied to the output, which is written SPLIT
// (ah, al bf16) as the next layer's pre-split A operand.
template <int ACTOUT>
__global__ void k_edge4(const unsigned short* __restrict__ glh, const float* __restrict__ gr,
                        const float* __restrict__ att, const int* __restrict__ rowptr,
                        const int* __restrict__ csr_src,
                        unsigned short* __restrict__ oah, unsigned short* __restrict__ oal,
                        int n) {
  int wid = (int)((blockIdx.x * blockDim.x + threadIdx.x) >> 6);
  if (wid >= n) return;
  int lane = threadIdx.x & 63;
  int p0 = rowptr[wid], p1 = rowptr[wid + 1];
  ushort2* pah = reinterpret_cast<ushort2*>(oah + (size_t)wid * 128) + lane;
  ushort2* pal = reinterpret_cast<ushort2*>(oal + (size_t)wid * 128) + lane;
  if (p1 <= p0) { *pah = make_ushort2(0, 0); *pal = make_ushort2(0, 0); return; }
  const float2 grv = reinterpret_cast<const float2*>(gr + (size_t)wid * 128)[lane];
  const float2 attv = reinterpret_cast<const float2*>(att)[lane];

  float l[8];
  float2 acc[8];
#pragma unroll
  for (int j = 0; j < 8; ++j) { l[j] = 0.f; acc[j] = make_float2(0.f, 0.f); }

#define LD(S) ({ ushort2 u_ = reinterpret_cast<const ushort2*>(glh + ((size_t)(S) << 7))[lane]; \
                 make_float2(bf2f(u_.x), bf2f(u_.y)); })
#define UPD4(J, G)                                                     \
  {                                                                    \
    float vx = (G).x + grv.x; vx = vx > 0.f ? vx : 0.2f * vx;          \
    float vy = (G).y + grv.y; vy = vy > 0.f ? vy : 0.2f * vy;          \
    float part = fmaf(vx, attv.x, vy * attv.y);                        \
    part += __shfl_xor(part, 1);                                       \
    part += __shfl_xor(part, 2);                                       \
    part += __shfl_xor(part, 4);                                       \
    part += __shfl_xor(part, 8);                                       \
    float w = __expf(part);                                            \
    l[J] += w;                                                         \
    acc[J].x = fmaf(w, (G).x, acc[J].x);                               \
    acc[J].y = fmaf(w, (G).y, acc[J].y);                               \
  }

  for (int base = p0; base < p1; base += 64) {
    int nv = p1 - base; if (nv > 64) nv = 64;
    int sv = (base + lane < p1) ? csr_src[base + lane] : 0;
    int i = 0;
    for (; i + 8 <= nv; i += 8) {
      int s0 = __shfl(sv, i + 0), s1 = __shfl(sv, i + 1);
      int s2 = __shfl(sv, i + 2), s3 = __shfl(sv, i + 3);
      int s4 = __shfl(sv, i + 4), s5 = __shfl(sv, i + 5);
      int s6 = __shfl(sv, i + 6), s7 = __shfl(sv, i + 7);
      float2 g0 = LD(s0), g1 = LD(s1), g2 = LD(s2), g3 = LD(s3);
      float2 g4 = LD(s4), g5 = LD(s5), g6 = LD(s6), g7 = LD(s7);
      UPD4(0, g0); UPD4(1, g1); UPD4(2, g2); UPD4(3, g3);
      UPD4(4, g4); UPD4(5, g5); UPD4(6, g6); UPD4(7, g7);
    }
    // remainder: STATIC chain 0 only (rule #20)
    for (; i < nv; ++i) {
      int s0 = __shfl(sv, i);
      float2 g0 = LD(s0);
      UPD4(0, g0);
    }
  }
#undef UPD4
#undef LD

  float lt = 0.f;
  float2 at = make_float2(0.f, 0.f);
#pragma unroll
  for (int j = 0; j < 8; ++j) {
    lt += l[j];
    at.x += acc[j].x;
    at.y += acc[j].y;
  }
  float inv = 1.f / (lt + 1e-16f);
  float ox = at.x * inv, oy = at.y * inv;
  if (ACTOUT == 1) {
    ox = ox > 0.f ? ox : (__expf(ox) - 1.f);
    oy = oy > 0.f ? oy : (__expf(oy) - 1.f);
  } else {
    ox = fmaxf(ox, 0.f);
    oy = fmaxf(oy, 0.f);
  }
  float rx, ry;
  unsigned short hx = (unsigned short)bf16rne(ox, &rx);
  unsigned short hy = (unsigned short)bf16rne(oy, &ry);
  unsigned short lx = (unsigned short)bf16rne(ox - rx, nullptr);
  unsigned short ly = (unsigned short)bf16rne(oy - ry, nullptr);
  *pah = make_ushort2(hx, hy);
  *pal = make_ushort2(lx, ly);
}

// ---------------- layer-3 edge + fused log_softmax: 2 dsts/wave, no-max --------
__global__ void k_edge1ls(const unsigned short* __restrict__ glh, const float* __restrict__ gr,
                          const float* __restrict__ att, const int* __restrict__ rowptr,
                          const int* __restrict__ csr_src, float* __restrict__ outf, int n) {
  int wv = (int)((blockIdx.x * blockDim.x + threadIdx.x) >> 6);
  int lane = threadIdx.x & 63;
  int half = lane >> 5, hl = lane & 31;
  int d = wv * 2 + half;
  if (d >= n) d = n - 1;
  bool fok = hl < 20;
  float2 grv = fok ? reinterpret_cast<const float2*>(gr + (size_t)d * 40)[hl]
                   : make_float2(0.f, 0.f);
  float2 attv = fok ? reinterpret_cast<const float2*>(att)[hl] : make_float2(0.f, 0.f);
  int p0 = rowptr[d], p1 = rowptr[d + 1];
  int ec = p1 - p0;
  int nch = (ec + 31) >> 5;
  { int o = __shfl_xor(nch, 32); nch = nch > o ? nch : o; }

  float l0 = 0.f, l1 = 0.f;
  float2 a0 = make_float2(0.f, 0.f), a1 = make_float2(0.f, 0.f);

  for (int c = 0; c < nch; ++c) {
    int base = p0 + c * 32;
    int sv = (base + hl < p1) ? csr_src[base + hl] : 0;
    int nv = p1 - base;
    nv = nv < 0 ? 0 : (nv > 32 ? 32 : nv);
    int nvmax = nv;
    { int o = __shfl_xor(nvmax, 32); nvmax = nvmax > o ? nvmax : o; }
    for (int i = 0; i < nvmax; i += 2) {
      int s0 = __shfl(sv, (half << 5) + i);
      int s1 = __shfl(sv, (half << 5) + i + 1);
      bool v0 = i < nv, v1 = (i + 1) < nv;
      float2 g0 = make_float2(0.f, 0.f), g1 = make_float2(0.f, 0.f);
      if (v0 && fok) { ushort2 u = reinterpret_cast<const ushort2*>(glh + (size_t)s0 * 40)[hl]; g0 = make_float2(bf2f(u.x), bf2f(u.y)); }
      if (v1 && fok) { ushort2 u = reinterpret_cast<const ushort2*>(glh + (size_t)s1 * 40)[hl]; g1 = make_float2(bf2f(u.x), bf2f(u.y)); }
      float e0x = g0.x + grv.x; e0x = e0x > 0.f ? e0x : 0.2f * e0x;
      float e0y = g0.y + grv.y; e0y = e0y > 0.f ? e0y : 0.2f * e0y;
      float pt0 = fmaf(e0x, attv.x, e0y * attv.y);
      float e1x = g1.x + grv.x; e1x = e1x > 0.f ? e1x : 0.2f * e1x;
      float e1y = g1.y + grv.y; e1y = e1y > 0.f ? e1y : 0.2f * e1y;
      float pt1 = fmaf(e1x, attv.x, e1y * attv.y);
#pragma unroll
      for (int o = 1; o < 32; o <<= 1) {
        pt0 += __shfl_xor(pt0, o);
        pt1 += __shfl_xor(pt1, o);
      }
      float w0 = v0 ? __expf(pt0) : 0.f;
      float w1 = v1 ? __expf(pt1) : 0.f;
      l0 += w0;
      a0.x = fmaf(w0, g0.x, a0.x);
      a0.y = fmaf(w0, g0.y, a0.y);
      l1 += w1;
      a1.x = fmaf(w1, g1.x, a1.x);
      a1.y = fmaf(w1, g1.y, a1.y);
    }
  }

  float lt = l0 + l1;
  float inv = 1.f / (lt + 1e-16f);
  float ox = (a0.x + a1.x) * inv;
  float oy = (a0.y + a1.y) * inv;

  float mx = fok ? fmaxf(ox, oy) : -INFINITY;
#pragma unroll
  for (int o = 1; o < 32; o <<= 1) mx = fmaxf(mx, __shfl_xor(mx, o));
  float ex = fok ? (__expf(ox - mx) + __expf(oy - mx)) : 0.f;
  float sm = ex;
#pragma unroll
  for (int o = 1; o < 32; o <<= 1) sm += __shfl_xor(sm, o);
  float lg = logf(sm);
  if (fok) {
    float2* po = reinterpret_cast<float2*>(outf + (size_t)d * 40);
    po[hl] = make_float2(ox - mx - lg, oy - mx - lg);
  }
}

static inline int cdiv(long long a, int b) { return (int)((a + b - 1) / b); }

extern "C" void kernel_launch(void* const* d_in, const int* in_sizes, int n_in,
                              void* d_out, int out_size, void* d_ws, size_t ws_size,
                              hipStream_t stream) {
  const float* x    = (const float*)d_in[0];
  const float* Wl1  = (const float*)d_in[1];
  const float* Wr1  = (const float*)d_in[2];
  const float* att1 = (const float*)d_in[3];
  const float* Wl2  = (const float*)d_in[4];
  const float* Wr2  = (const float*)d_in[5];
  const float* att2 = (const float*)d_in[6];
  const float* Wl3  = (const float*)d_in[7];
  const float* Wr3  = (const float*)d_in[8];
  const float* att3 = (const float*)d_in[9];
  const int*   ei   = (const int*)d_in[10];

  const int N = in_sizes[0] / 128;   // 50000
  const int E = in_sizes[10] / 2;    // 800000
  const int* src = ei;
  const int* dst = ei + E;

  short* wt = (short*)d_ws;
  short* wl1h = wt +      0;  short* wl1l = wt +  16384;
  short* wr1h = wt +  32768;  short* wr1l = wt +  49152;
  short* wl2h = wt +  65536;  short* wl2l = wt +  81920;
  short* wr2h = wt +  98304;  short* wr2l = wt + 114688;
  short* wl3h = wt + 131072;  short* wl3l = wt + 137216;
  short* wr3h = wt + 143360;  short* wr3l = wt + 149504;

  // 155648 shorts of weights (311296 B, 16B-aligned end)
  unsigned short* ah  = (unsigned short*)(wt + 155648);          // N*128 bf16
  unsigned short* al  = ah + (size_t)N * 128;                    // N*128 bf16
  float* bufGR        = (float*)(al + (size_t)N * 128);          // N*128 f32
  unsigned short* glh = (unsigned short*)(bufGR + (size_t)N * 128); // N*128 bf16
  int*   cnt    = (int*)(glh + (size_t)N * 128);                 // N
  int*   rowptr = cnt + N;                                       // N+1
  int*   cur    = rowptr + N + 1;                                // N
  int*   csrS   = cur + N;                                       // E
  int*   bsum   = csrS + E;                                      // 64
  int*   boff   = bsum + 64;                                     // 64

  float* outf = (float*)d_out;

  const int nb = cdiv(N, 1024);  // 49

  // ---------------- CSR build + W/X preprocess ----------------
  hipMemsetAsync(cnt, 0, (size_t)N * sizeof(int), stream);
  k_hist<<<cdiv(E, TPB), TPB, 0, stream>>>(dst, cnt, E);
  k_prepW6<<<dim3(64, 6), TPB, 0, stream>>>(Wl1, Wr1, Wl2, Wr2, Wl3, Wr3, wt);
  k_prepX<<<cdiv((long long)N * 16, TPB), TPB, 0, stream>>>(x, ah, al, N * 16);
  k_scan1<<<nb, 1024, 0, stream>>>(cnt, rowptr, bsum, N);
  k_scan2<<<1, 64, 0, stream>>>(bsum, boff, nb, rowptr, N);
  k_scan3<<<cdiv(N, TPB), TPB, 0, stream>>>(rowptr, boff, cur, N);
  k_fill<<<cdiv(E, TPB), TPB, 0, stream>>>(src, dst, cur, csrS, E);

  // ---------------- layer 1 ----------------
  k_gemm_mfma<<<cdiv(N, 16), 256, 0, stream>>>(ah, al, wl1h, wl1l, wr1h, wr1l, glh, bufGR, N);
  k_edge4<1><<<cdiv(N, 4), TPB, 0, stream>>>(glh, bufGR, att1, rowptr, csrS, ah, al, N);

  // ---------------- layer 2 ----------------
  k_gemm_mfma<<<cdiv(N, 16), 256, 0, stream>>>(ah, al, wl2h, wl2l, wr2h, wr2l, glh, bufGR, N);
  k_edge4<2><<<cdiv(N, 4), TPB, 0, stream>>>(glh, bufGR, att2, rowptr, csrS, ah, al, N);

  // ---------------- layer 3 + fused log_softmax ----------------
  k_gemm_mfma3<<<cdiv(N, 16), 192, 0, stream>>>(ah, al, wl3h, wl3l, wr3h, wr3l, glh, bufGR, N);
  k_edge1ls<<<cdiv(cdiv(N, 2), 4), TPB, 0, stream>>>(glh, bufGR, att3, rowptr, csrS, outf, N);
}

// Round 13
// 418.276 us; speedup vs baseline: 1.2186x; 1.2186x over previous
//
#include <hip/hip_runtime.h>
#include <math.h>

// GATv2 x3 + log_softmax for MI355X (gfx950).
// Round 13: GEMM B-reuse via LDS-A + register-B.
//   R12 analysis: B traffic = (N/16 row-tiles) x 128KB = 400MB/GEMM from L3
//   (streaming A/C thrash the 4MB XCD L2) ~= 70us -- invariant under R10-R12's
//   changes. Fix: 64-row blocks; A-tile staged in LDS once (padded rows,
//   2-way-free banks); each of 8 waves owns one col-group with its whole B
//   operand hoisted into 64 VGPRs; loops 4 row-tiles. B: 400->100MB.
// Edge phase unchanged from R12.

#define TPB 256

typedef __attribute__((ext_vector_type(8))) short short8v;   // 8 bf16
typedef __attribute__((ext_vector_type(4))) float f32x4;

__device__ __forceinline__ short bf16rne(float v, float* recon) {
  unsigned u = __float_as_uint(v);
  unsigned r = (u + 0x7FFFu + ((u >> 16) & 1u)) >> 16;
  if (recon) *recon = __uint_as_float(r << 16);
  return (short)r;
}
__device__ __forceinline__ float bf2f(unsigned short u) {
  return __uint_as_float((unsigned)u << 16);
}

// ---------------- x -> (ah, al) split bf16 ----------------
__global__ void k_prepX(const float* __restrict__ x, unsigned short* __restrict__ ah,
                        unsigned short* __restrict__ al, int total8) {
  int t = blockIdx.x * blockDim.x + threadIdx.x;
  if (t >= total8) return;
  const float4* px = reinterpret_cast<const float4*>(x) + (size_t)t * 2;
  float4 a = px[0], b = px[1];
  float av[8] = {a.x, a.y, a.z, a.w, b.x, b.y, b.z, b.w};
  short8v h, l;
#pragma unroll
  for (int j = 0; j < 8; ++j) {
    float vh;
    h[j] = bf16rne(av[j], &vh);
    l[j] = bf16rne(av[j] - vh, nullptr);
  }
  *reinterpret_cast<short8v*>(ah + (size_t)t * 8) = h;
  *reinterpret_cast<short8v*>(al + (size_t)t * 8) = l;
}

// ---------------- merged W preprocess ----------------
__global__ void k_prepW6(const float* __restrict__ s0, const float* __restrict__ s1,
                         const float* __restrict__ s2, const float* __restrict__ s3,
                         const float* __restrict__ s4, const float* __restrict__ s5,
                         short* __restrict__ wt) {
  int y = blockIdx.y;
  const float* W; short* hi; int M, Mp;
  if (y < 4) {
    W = (y == 0) ? s0 : (y == 1) ? s1 : (y == 2) ? s2 : s3;
    hi = wt + y * 32768; M = 128; Mp = 128;
  } else {
    W = (y == 4) ? s4 : s5;
    hi = wt + 131072 + (y - 4) * 12288; M = 40; Mp = 48;
  }
  short* lo = hi + 128 * Mp;
  int t = blockIdx.x * blockDim.x + threadIdx.x;
  if (t >= 128 * Mp) return;
  int m = t % Mp, k = t / Mp;
  float v = (m < M) ? W[k * M + m] : 0.f;
  float vh;
  short h = bf16rne(v, &vh);
  short l = bf16rne(v - vh, nullptr);
  hi[(size_t)m * 128 + k] = h;
  lo[(size_t)m * 128 + k] = l;
}

// ---------------- LDS-A / reg-B MFMA GEMM ----------------
// Block: 64 rows, NCG waves; wave w owns col-group w (cols w*16..+15).
// A-tile (split bf16) staged to LDS with 272B row pitch (16B-aligned,
// 2-way-free banks). B operand (4 k0 x {bh,bl,ch,cl}) hoisted to 64 VGPRs.
template <int NCG, int MOUT>
__global__ __launch_bounds__(NCG * 64) void k_gemm_lds(
    const unsigned short* __restrict__ ah, const unsigned short* __restrict__ al,
    const short* __restrict__ blh, const short* __restrict__ bll,
    const short* __restrict__ brh, const short* __restrict__ brl,
    unsigned short* __restrict__ glh, float* __restrict__ gr, int n) {
  const int K = 128;
  __shared__ unsigned short aldsH[64][136];  // 272B pitch
  __shared__ unsigned short aldsL[64][136];

  int lane = threadIdx.x & 63;
  int w = threadIdx.x >> 6;      // col-group
  int rbase = blockIdx.x * 64;

  // ---- hoist B fragments (issue first; overlaps staging) ----
  int bbase = (w * 16 + (lane & 15)) * K + (lane >> 4) * 8;
  short8v Bh[4], Bl[4], Ch[4], Cl[4];
#pragma unroll
  for (int k = 0; k < 4; ++k) {
    Bh[k] = *reinterpret_cast<const short8v*>(blh + bbase + k * 32);
    Bl[k] = *reinterpret_cast<const short8v*>(bll + bbase + k * 32);
    Ch[k] = *reinterpret_cast<const short8v*>(brh + bbase + k * 32);
    Cl[k] = *reinterpret_cast<const short8v*>(brl + bbase + k * 32);
  }

  // ---- stage A-tile into LDS (rows clamped; 16B chunks) ----
  for (int c = threadIdx.x; c < 64 * 16; c += NCG * 64) {
    int row = c >> 4, seg = c & 15;
    int grow = rbase + row;
    if (grow >= n) grow = n - 1;
    short8v hv = *reinterpret_cast<const short8v*>(ah + (size_t)grow * 128 + seg * 8);
    short8v lv = *reinterpret_cast<const short8v*>(al + (size_t)grow * 128 + seg * 8);
    *reinterpret_cast<short8v*>(&aldsH[row][seg * 8]) = hv;
    *reinterpret_cast<short8v*>(&aldsL[row][seg * 8]) = lv;
  }
  __syncthreads();

  int arow_l = lane & 15;
  int kb = (lane >> 4) * 8;
  int ccol = lane & 15;
  int col = w * 16 + ccol;

  // ---- 4 row-tiles ----
#pragma unroll
  for (int t = 0; t < 4; ++t) {
    int r0 = t * 16 + arow_l;
    f32x4 accL = (f32x4)(0.f), accR = (f32x4)(0.f);
#pragma unroll
    for (int k = 0; k < 4; ++k) {
      short8v AHf = *reinterpret_cast<const short8v*>(&aldsH[r0][k * 32 + kb]);
      short8v ALf = *reinterpret_cast<const short8v*>(&aldsL[r0][k * 32 + kb]);
      accL = __builtin_amdgcn_mfma_f32_16x16x32_bf16(AHf, Bh[k], accL, 0, 0, 0);
      accL = __builtin_amdgcn_mfma_f32_16x16x32_bf16(AHf, Bl[k], accL, 0, 0, 0);
      accL = __builtin_amdgcn_mfma_f32_16x16x32_bf16(ALf, Bh[k], accL, 0, 0, 0);
      accR = __builtin_amdgcn_mfma_f32_16x16x32_bf16(AHf, Ch[k], accR, 0, 0, 0);
      accR = __builtin_amdgcn_mfma_f32_16x16x32_bf16(AHf, Cl[k], accR, 0, 0, 0);
      accR = __builtin_amdgcn_mfma_f32_16x16x32_bf16(ALf, Ch[k], accR, 0, 0, 0);
    }
    int crow = rbase + t * 16 + (lane >> 4) * 4;
#pragma unroll
    for (int j = 0; j < 4; ++j) {
      int r = crow + j;
      if (r < n && col < MOUT) {
        glh[(size_t)r * MOUT + col] = (unsigned short)bf16rne(accL[j], nullptr);
        gr[(size_t)r * MOUT + col] = accR[j];
      }
    }
  }
}

// ---------------- CSR build ----------------
__global__ void k_hist(const int* __restrict__ dst, int* __restrict__ cnt, int E) {
  int e = blockIdx.x * blockDim.x + threadIdx.x;
  if (e < E) atomicAdd(&cnt[dst[e]], 1);
}

__global__ void k_scan1(const int* __restrict__ cnt, int* __restrict__ rowptr,
                        int* __restrict__ bsum, int n) {
  __shared__ int wsum[16];
  int i = blockIdx.x * 1024 + threadIdx.x;
  int lane = threadIdx.x & 63, wid = threadIdx.x >> 6;
  int v = (i < n) ? cnt[i] : 0;
  int x = v;
#pragma unroll
  for (int off = 1; off < 64; off <<= 1) {
    int t = __shfl_up(x, off);
    if (lane >= off) x += t;
  }
  if (lane == 63) wsum[wid] = x;
  __syncthreads();
  if (wid == 0) {
    int wv = (lane < 16) ? wsum[lane] : 0;
#pragma unroll
    for (int off = 1; off < 16; off <<= 1) {
      int t = __shfl_up(wv, off);
      if (lane >= off) wv += t;
    }
    if (lane < 16) wsum[lane] = wv;
  }
  __syncthreads();
  int woff = wid ? wsum[wid - 1] : 0;
  if (i < n) rowptr[i] = woff + x - v;
  if (threadIdx.x == 1023) bsum[blockIdx.x] = wsum[15];
}

__global__ void k_scan2(const int* __restrict__ bsum, int* __restrict__ boff, int nb,
                        int* __restrict__ rowptr, int n) {
  int lane = threadIdx.x;
  int v = (lane < nb) ? bsum[lane] : 0;
  int x = v;
#pragma unroll
  for (int off = 1; off < 64; off <<= 1) {
    int t = __shfl_up(x, off);
    if (lane >= off) x += t;
  }
  if (lane < nb) boff[lane] = x - v;
  if (lane == 63) rowptr[n] = x;
}

__global__ void k_scan3(int* __restrict__ rowptr, const int* __restrict__ boff,
                        int* __restrict__ cur, int n) {
  int i = blockIdx.x * blockDim.x + threadIdx.x;
  if (i < n) {
    int r = rowptr[i] + boff[i >> 10];
    rowptr[i] = r;
    cur[i] = r;
  }
}

__global__ void k_fill(const int* __restrict__ src, const int* __restrict__ dst,
                       int* __restrict__ cur, int* __restrict__ csr_src, int E) {
  int e = blockIdx.x * blockDim.x + threadIdx.x;
  if (e >= E) return;
  int pos = atomicAdd(&cur[dst[e]], 1);
  csr_src[pos] = src[e];
}

// ---- fused per-dst edge kernel, H=4 F=32, 8 chains, no-max ----
// ACTOUT applied to output; output written split (ah, al) for next GEMM.
template <int ACTOUT>
__global__ void k_edge4(const unsigned short* __restrict__ glh, const float* __restrict__ gr,
                        const float* __restrict__ att, const int* __restrict__ rowptr,
                        const int* __restrict__ csr_src,
                        unsigned short* __restrict__ oah, unsigned short* __restrict__ oal,
                        int n) {
  int wid = (int)((blockIdx.x * blockDim.x + threadIdx.x) >> 6);
  if (wid >= n) return;
  int lane = threadIdx.x & 63;
  int p0 = rowptr[wid], p1 = rowptr[wid + 1];
  ushort2* pah = reinterpret_cast<ushort2*>(oah + (size_t)wid * 128) + lane;
  ushort2* pal = reinterpret_cast<ushort2*>(oal + (size_t)wid * 128) + lane;
  if (p1 <= p0) { *pah = make_ushort2(0, 0); *pal = make_ushort2(0, 0); return; }
  const float2 grv = reinterpret_cast<const float2*>(gr + (size_t)wid * 128)[lane];
  const float2 attv = reinterpret_cast<const float2*>(att)[lane];

  float l[8];
  float2 acc[8];
#pragma unroll
  for (int j = 0; j < 8; ++j) { l[j] = 0.f; acc[j] = make_float2(0.f, 0.f); }

#define LD(S) ({ ushort2 u_ = reinterpret_cast<const ushort2*>(glh + ((size_t)(S) << 7))[lane]; \
                 make_float2(bf2f(u_.x), bf2f(u_.y)); })
#define UPD4(J, G)                                                     \
  {                                                                    \
    float vx = (G).x + grv.x; vx = vx > 0.f ? vx : 0.2f * vx;          \
    float vy = (G).y + grv.y; vy = vy > 0.f ? vy : 0.2f * vy;          \
    float part = fmaf(vx, attv.x, vy * attv.y);                        \
    part += __shfl_xor(part, 1);                                       \
    part += __shfl_xor(part, 2);                                       \
    part += __shfl_xor(part, 4);                                       \
    part += __shfl_xor(part, 8);                                       \
    float w = __expf(part);                                            \
    l[J] += w;                                                         \
    acc[J].x = fmaf(w, (G).x, acc[J].x);                               \
    acc[J].y = fmaf(w, (G).y, acc[J].y);                               \
  }

  for (int base = p0; base < p1; base += 64) {
    int nv = p1 - base; if (nv > 64) nv = 64;
    int sv = (base + lane < p1) ? csr_src[base + lane] : 0;
    int i = 0;
    for (; i + 8 <= nv; i += 8) {
      int s0 = __shfl(sv, i + 0), s1 = __shfl(sv, i + 1);
      int s2 = __shfl(sv, i + 2), s3 = __shfl(sv, i + 3);
      int s4 = __shfl(sv, i + 4), s5 = __shfl(sv, i + 5);
      int s6 = __shfl(sv, i + 6), s7 = __shfl(sv, i + 7);
      float2 g0 = LD(s0), g1 = LD(s1), g2 = LD(s2), g3 = LD(s3);
      float2 g4 = LD(s4), g5 = LD(s5), g6 = LD(s6), g7 = LD(s7);
      UPD4(0, g0); UPD4(1, g1); UPD4(2, g2); UPD4(3, g3);
      UPD4(4, g4); UPD4(5, g5); UPD4(6, g6); UPD4(7, g7);
    }
    // remainder: STATIC chain 0 only (rule #20)
    for (; i < nv; ++i) {
      int s0 = __shfl(sv, i);
      float2 g0 = LD(s0);
      UPD4(0, g0);
    }
  }
#undef UPD4
#undef LD

  float lt = 0.f;
  float2 at = make_float2(0.f, 0.f);
#pragma unroll
  for (int j = 0; j < 8; ++j) {
    lt += l[j];
    at.x += acc[j].x;
    at.y += acc[j].y;
  }
  float inv = 1.f / (lt + 1e-16f);
  float ox = at.x * inv, oy = at.y * inv;
  if (ACTOUT == 1) {
    ox = ox > 0.f ? ox : (__expf(ox) - 1.f);
    oy = oy > 0.f ? oy : (__expf(oy) - 1.f);
  } else {
    ox = fmaxf(ox, 0.f);
    oy = fmaxf(oy, 0.f);
  }
  float rx, ry;
  unsigned short hx = (unsigned short)bf16rne(ox, &rx);
  unsigned short hy = (unsigned short)bf16rne(oy, &ry);
  unsigned short lx = (unsigned short)bf16rne(ox - rx, nullptr);
  unsigned short ly = (unsigned short)bf16rne(oy - ry, nullptr);
  *pah = make_ushort2(hx, hy);
  *pal = make_ushort2(lx, ly);
}

// ---------------- layer-3 edge + fused log_softmax: 2 dsts/wave, no-max --------
__global__ void k_edge1ls(const unsigned short* __restrict__ glh, const float* __restrict__ gr,
                          const float* __restrict__ att, const int* __restrict__ rowptr,
                          const int* __restrict__ csr_src, float* __restrict__ outf, int n) {
  int wv = (int)((blockIdx.x * blockDim.x + threadIdx.x) >> 6);
  int lane = threadIdx.x & 63;
  int half = lane >> 5, hl = lane & 31;
  int d = wv * 2 + half;
  if (d >= n) d = n - 1;
  bool fok = hl < 20;
  float2 grv = fok ? reinterpret_cast<const float2*>(gr + (size_t)d * 40)[hl]
                   : make_float2(0.f, 0.f);
  float2 attv = fok ? reinterpret_cast<const float2*>(att)[hl] : make_float2(0.f, 0.f);
  int p0 = rowptr[d], p1 = rowptr[d + 1];
  int ec = p1 - p0;
  int nch = (ec + 31) >> 5;
  { int o = __shfl_xor(nch, 32); nch = nch > o ? nch : o; }

  float l0 = 0.f, l1 = 0.f;
  float2 a0 = make_float2(0.f, 0.f), a1 = make_float2(0.f, 0.f);

  for (int c = 0; c < nch; ++c) {
    int base = p0 + c * 32;
    int sv = (base + hl < p1) ? csr_src[base + hl] : 0;
    int nv = p1 - base;
    nv = nv < 0 ? 0 : (nv > 32 ? 32 : nv);
    int nvmax = nv;
    { int o = __shfl_xor(nvmax, 32); nvmax = nvmax > o ? nvmax : o; }
    for (int i = 0; i < nvmax; i += 2) {
      int s0 = __shfl(sv, (half << 5) + i);
      int s1 = __shfl(sv, (half << 5) + i + 1);
      bool v0 = i < nv, v1 = (i + 1) < nv;
      float2 g0 = make_float2(0.f, 0.f), g1 = make_float2(0.f, 0.f);
      if (v0 && fok) { ushort2 u = reinterpret_cast<const ushort2*>(glh + (size_t)s0 * 40)[hl]; g0 = make_float2(bf2f(u.x), bf2f(u.y)); }
      if (v1 && fok) { ushort2 u = reinterpret_cast<const ushort2*>(glh + (size_t)s1 * 40)[hl]; g1 = make_float2(bf2f(u.x), bf2f(u.y)); }
      float e0x = g0.x + grv.x; e0x = e0x > 0.f ? e0x : 0.2f * e0x;
      float e0y = g0.y + grv.y; e0y = e0y > 0.f ? e0y : 0.2f * e0y;
      float pt0 = fmaf(e0x, attv.x, e0y * attv.y);
      float e1x = g1.x + grv.x; e1x = e1x > 0.f ? e1x : 0.2f * e1x;
      float e1y = g1.y + grv.y; e1y = e1y > 0.f ? e1y : 0.2f * e1y;
      float pt1 = fmaf(e1x, attv.x, e1y * attv.y);
#pragma unroll
      for (int o = 1; o < 32; o <<= 1) {
        pt0 += __shfl_xor(pt0, o);
        pt1 += __shfl_xor(pt1, o);
      }
      float w0 = v0 ? __expf(pt0) : 0.f;
      float w1 = v1 ? __expf(pt1) : 0.f;
      l0 += w0;
      a0.x = fmaf(w0, g0.x, a0.x);
      a0.y = fmaf(w0, g0.y, a0.y);
      l1 += w1;
      a1.x = fmaf(w1, g1.x, a1.x);
      a1.y = fmaf(w1, g1.y, a1.y);
    }
  }

  float lt = l0 + l1;
  float inv = 1.f / (lt + 1e-16f);
  float ox = (a0.x + a1.x) * inv;
  float oy = (a0.y + a1.y) * inv;

  float mx = fok ? fmaxf(ox, oy) : -INFINITY;
#pragma unroll
  for (int o = 1; o < 32; o <<= 1) mx = fmaxf(mx, __shfl_xor(mx, o));
  float ex = fok ? (__expf(ox - mx) + __expf(oy - mx)) : 0.f;
  float sm = ex;
#pragma unroll
  for (int o = 1; o < 32; o <<= 1) sm += __shfl_xor(sm, o);
  float lg = logf(sm);
  if (fok) {
    float2* po = reinterpret_cast<float2*>(outf + (size_t)d * 40);
    po[hl] = make_float2(ox - mx - lg, oy - mx - lg);
  }
}

static inline int cdiv(long long a, int b) { return (int)((a + b - 1) / b); }

extern "C" void kernel_launch(void* const* d_in, const int* in_sizes, int n_in,
                              void* d_out, int out_size, void* d_ws, size_t ws_size,
                              hipStream_t stream) {
  const float* x    = (const float*)d_in[0];
  const float* Wl1  = (const float*)d_in[1];
  const float* Wr1  = (const float*)d_in[2];
  const float* att1 = (const float*)d_in[3];
  const float* Wl2  = (const float*)d_in[4];
  const float* Wr2  = (const float*)d_in[5];
  const float* att2 = (const float*)d_in[6];
  const float* Wl3  = (const float*)d_in[7];
  const float* Wr3  = (const float*)d_in[8];
  const float* att3 = (const float*)d_in[9];
  const int*   ei   = (const int*)d_in[10];

  const int N = in_sizes[0] / 128;   // 50000
  const int E = in_sizes[10] / 2;    // 800000
  const int* src = ei;
  const int* dst = ei + E;

  short* wt = (short*)d_ws;
  short* wl1h = wt +      0;  short* wl1l = wt +  16384;
  short* wr1h = wt +  32768;  short* wr1l = wt +  49152;
  short* wl2h = wt +  65536;  short* wl2l = wt +  81920;
  short* wr2h = wt +  98304;  short* wr2l = wt + 114688;
  short* wl3h = wt + 131072;  short* wl3l = wt + 137216;
  short* wr3h = wt + 143360;  short* wr3l = wt + 149504;

  unsigned short* ah  = (unsigned short*)(wt + 155648);          // N*128 bf16
  unsigned short* al  = ah + (size_t)N * 128;                    // N*128 bf16
  float* bufGR        = (float*)(al + (size_t)N * 128);          // N*128 f32
  unsigned short* glh = (unsigned short*)(bufGR + (size_t)N * 128); // N*128 bf16
  int*   cnt    = (int*)(glh + (size_t)N * 128);                 // N
  int*   rowptr = cnt + N;                                       // N+1
  int*   cur    = rowptr + N + 1;                                // N
  int*   csrS   = cur + N;                                       // E
  int*   bsum   = csrS + E;                                      // 64
  int*   boff   = bsum + 64;                                     // 64

  float* outf = (float*)d_out;

  const int nb = cdiv(N, 1024);  // 49

  // ---------------- CSR build + W/X preprocess ----------------
  hipMemsetAsync(cnt, 0, (size_t)N * sizeof(int), stream);
  k_hist<<<cdiv(E, TPB), TPB, 0, stream>>>(dst, cnt, E);
  k_prepW6<<<dim3(64, 6), TPB, 0, stream>>>(Wl1, Wr1, Wl2, Wr2, Wl3, Wr3, wt);
  k_prepX<<<cdiv((long long)N * 16, TPB), TPB, 0, stream>>>(x, ah, al, N * 16);
  k_scan1<<<nb, 1024, 0, stream>>>(cnt, rowptr, bsum, N);
  k_scan2<<<1, 64, 0, stream>>>(bsum, boff, nb, rowptr, N);
  k_scan3<<<cdiv(N, TPB), TPB, 0, stream>>>(rowptr, boff, cur, N);
  k_fill<<<cdiv(E, TPB), TPB, 0, stream>>>(src, dst, cur, csrS, E);

  // ---------------- layer 1 ----------------
  k_gemm_lds<8, 128><<<cdiv(N, 64), 512, 0, stream>>>(ah, al, wl1h, wl1l, wr1h, wr1l, glh, bufGR, N);
  k_edge4<1><<<cdiv(N, 4), TPB, 0, stream>>>(glh, bufGR, att1, rowptr, csrS, ah, al, N);

  // ---------------- layer 2 ----------------
  k_gemm_lds<8, 128><<<cdiv(N, 64), 512, 0, stream>>>(ah, al, wl2h, wl2l, wr2h, wr2l, glh, bufGR, N);
  k_edge4<2><<<cdiv(N, 4), TPB, 0, stream>>>(glh, bufGR, att2, rowptr, csrS, ah, al, N);

  // ---------------- layer 3 + fused log_softmax ----------------
  k_gemm_lds<3, 40><<<cdiv(N, 64), 192, 0, stream>>>(ah, al, wl3h, wl3l, wr3h, wr3l, glh, bufGR, N);
  k_edge1ls<<<cdiv(cdiv(N, 2), 4), TPB, 0, stream>>>(glh, bufGR, att3, rowptr, csrS, outf, N);
}